// Round 7
// baseline (235.768 us; speedup 1.0000x reference)
//
#include <hip/hip_runtime.h>
#include <hip/hip_bf16.h>
#include <stdint.h>

typedef __bf16 bf16x8 __attribute__((ext_vector_type(8)));
typedef __bf16 bf16x4 __attribute__((ext_vector_type(4)));
typedef float f32x4 __attribute__((ext_vector_type(4)));

#define DMODEL 1024
#define SEQ    2048
#define NHEAD  16
#define DK     64
#define MTOT   4096
#define KDIM   1024

// Explicit ISA-level drain before barriers that close a staging protocol
// (round-4 post-timing divergence fix; measured free).
#define DRAIN_VM_LGKM() asm volatile("s_waitcnt vmcnt(0) lgkmcnt(0)" ::: "memory")
#define DRAIN_LGKM()    asm volatile("s_waitcnt lgkmcnt(0)" ::: "memory")

__device__ __forceinline__ void gl2lds16(const void* g, void* l) {
  __builtin_amdgcn_global_load_lds((__attribute__((address_space(1))) void*)(g),
                                   (__attribute__((address_space(3))) void*)(l),
                                   16, 0, 0);
}

// ---------------- prep: f32 -> bf16 convert, q/k/v batched ----------------
__global__ __launch_bounds__(256) void k_cvt3(const float* __restrict__ q,
                                              const float* __restrict__ k,
                                              const float* __restrict__ v,
                                              __bf16* __restrict__ oq,
                                              __bf16* __restrict__ ok,
                                              __bf16* __restrict__ ov,
                                              int n4) {
  const int which = blockIdx.y;
  const float* in = which == 0 ? q : (which == 1 ? k : v);
  __bf16* out = which == 0 ? oq : (which == 1 ? ok : ov);
  const int i = blockIdx.x * 256 + threadIdx.x;
  if (i >= n4) return;
  const float4 f = ((const float4*)in)[i];
  bf16x4 o = { (__bf16)f.x, (__bf16)f.y, (__bf16)f.z, (__bf16)f.w };
  ((bf16x4*)out)[i] = o;
}

// ---------------- prep: W [K][N] f32 -> WT [N][K] bf16, 4 weights batched ----------------
__global__ __launch_bounds__(256) void k_transpose4(const float* __restrict__ w0,
                                                    const float* __restrict__ w1,
                                                    const float* __restrict__ w2,
                                                    const float* __restrict__ w3,
                                                    __bf16* __restrict__ t0,
                                                    __bf16* __restrict__ t1,
                                                    __bf16* __restrict__ t2,
                                                    __bf16* __restrict__ t3) {
  const int z = blockIdx.z;
  const float* W = z == 0 ? w0 : (z == 1 ? w1 : (z == 2 ? w2 : w3));
  __bf16* WT = z == 0 ? t0 : (z == 1 ? t1 : (z == 2 ? t2 : t3));
  __shared__ float tile[32][33];
  int n0 = blockIdx.x * 32, k0 = blockIdx.y * 32;
  int tx = threadIdx.x & 31, ty = threadIdx.x >> 5;
  #pragma unroll
  for (int i = ty; i < 32; i += 8)
    tile[i][tx] = W[(size_t)(k0 + i) * DMODEL + n0 + tx];
  __syncthreads();
  #pragma unroll
  for (int i = ty; i < 32; i += 8)
    WT[(size_t)(n0 + i) * DMODEL + k0 + tx] = (__bf16)tile[tx][i];
}

// ---------------- batched projection GEMM: z in {q,k,v}, 128x64 tile ----------------
// C[4096x1024] = A @ B (BT given [N][K]).  z=0/1 -> [B,H,S,DK]; z=2 -> VT [B,H,DK,S]
// 128x64 tile: grid (16,32,3) = 1536 blocks -> 6 blocks/CU (vs 1 at 128x128):
// these N=1024 GEMMs are latency/occupancy-bound, not staging-bound.
__global__ __launch_bounds__(256) void k_gemm_qkv(
    const __bf16* __restrict__ A0, const __bf16* __restrict__ A1, const __bf16* __restrict__ A2,
    const __bf16* __restrict__ W0, const __bf16* __restrict__ W1, const __bf16* __restrict__ W2,
    const float* __restrict__ bi0, const float* __restrict__ bi1, const float* __restrict__ bi2,
    __bf16* __restrict__ C0, __bf16* __restrict__ C1, __bf16* __restrict__ C2) {
  const int z = blockIdx.z;
  const __bf16* A  = z == 0 ? A0 : (z == 1 ? A1 : A2);
  const __bf16* BT = z == 0 ? W0 : (z == 1 ? W1 : W2);
  const float* bias = z == 0 ? bi0 : (z == 1 ? bi1 : bi2);
  __bf16* Cout = z == 0 ? C0 : (z == 1 ? C1 : C2);

  __shared__ __align__(16) __bf16 As[128 * 32];
  __shared__ __align__(16) __bf16 Bs[64 * 32];
  const int tid = threadIdx.x;
  const int lane = tid & 63;
  const int wv = tid >> 6;              // wave owns rows wv*32..wv*32+31
  const int m0 = blockIdx.y * 128, n0 = blockIdx.x * 64;
  const int lr = lane & 15, lg = lane >> 4;

  f32x4 acc[2][4] = {};

  for (int k0 = 0; k0 < KDIM; k0 += 32) {
    #pragma unroll
    for (int i = 0; i < 3; ++i) {
      int c = tid + i * 256;            // 0..767: 512 A-chunks + 256 B-chunks
      if (c < 512) {
        int row = c >> 2, seg = c & 3;
        gl2lds16(A + (size_t)(m0 + row) * KDIM + k0 + seg * 8, (char*)As + c * 16);
      } else {
        int c2 = c - 512;
        int row = c2 >> 2, seg = c2 & 3;
        gl2lds16(BT + (size_t)(n0 + row) * KDIM + k0 + seg * 8, (char*)Bs + c2 * 16);
      }
    }
    DRAIN_VM_LGKM();
    __syncthreads();
    bf16x8 af[2], bfr[4];
    #pragma unroll
    for (int mi = 0; mi < 2; ++mi)
      af[mi] = *(const bf16x8*)&As[(wv * 32 + mi * 16 + lr) * 32 + lg * 8];
    #pragma unroll
    for (int ni = 0; ni < 4; ++ni)
      bfr[ni] = *(const bf16x8*)&Bs[(ni * 16 + lr) * 32 + lg * 8];
    #pragma unroll
    for (int mi = 0; mi < 2; ++mi)
      #pragma unroll
      for (int ni = 0; ni < 4; ++ni)
        acc[mi][ni] = __builtin_amdgcn_mfma_f32_16x16x32_bf16(af[mi], bfr[ni], acc[mi][ni], 0, 0, 0);
    DRAIN_LGKM();
    __syncthreads();
  }

  #pragma unroll
  for (int mi = 0; mi < 2; ++mi)
    #pragma unroll
    for (int ni = 0; ni < 4; ++ni) {
      const int col = n0 + ni * 16 + lr;
      const float bv = bias[col];
      #pragma unroll
      for (int r = 0; r < 4; ++r) {
        const int row = m0 + wv * 32 + mi * 16 + lg * 4 + r;
        float v = acc[mi][ni][r] + bv;
        const int b = row >> 11, s = row & (SEQ - 1);
        const int h = col >> 6, dd = col & (DK - 1);
        if (z == 2)
          Cout[((size_t)(b * NHEAD + h) * DK + dd) * SEQ + s] = (__bf16)v;
        else
          Cout[((size_t)(b * NHEAD + h) * SEQ + s) * DK + dd] = (__bf16)v;
      }
    }
}

// ---------------- final GEMM: f32 out + bias, 128x64 tile ----------------
__global__ __launch_bounds__(256) void k_gemm_out(const __bf16* __restrict__ A,
                                                  const __bf16* __restrict__ BT,
                                                  const float* __restrict__ bias,
                                                  float* __restrict__ Cout) {
  __shared__ __align__(16) __bf16 As[128 * 32];
  __shared__ __align__(16) __bf16 Bs[64 * 32];
  const int tid = threadIdx.x;
  const int lane = tid & 63;
  const int wv = tid >> 6;
  const int m0 = blockIdx.y * 128, n0 = blockIdx.x * 64;
  const int lr = lane & 15, lg = lane >> 4;

  f32x4 acc[2][4] = {};

  for (int k0 = 0; k0 < KDIM; k0 += 32) {
    #pragma unroll
    for (int i = 0; i < 3; ++i) {
      int c = tid + i * 256;
      if (c < 512) {
        int row = c >> 2, seg = c & 3;
        gl2lds16(A + (size_t)(m0 + row) * KDIM + k0 + seg * 8, (char*)As + c * 16);
      } else {
        int c2 = c - 512;
        int row = c2 >> 2, seg = c2 & 3;
        gl2lds16(BT + (size_t)(n0 + row) * KDIM + k0 + seg * 8, (char*)Bs + c2 * 16);
      }
    }
    DRAIN_VM_LGKM();
    __syncthreads();
    bf16x8 af[2], bfr[4];
    #pragma unroll
    for (int mi = 0; mi < 2; ++mi)
      af[mi] = *(const bf16x8*)&As[(wv * 32 + mi * 16 + lr) * 32 + lg * 8];
    #pragma unroll
    for (int ni = 0; ni < 4; ++ni)
      bfr[ni] = *(const bf16x8*)&Bs[(ni * 16 + lr) * 32 + lg * 8];
    #pragma unroll
    for (int mi = 0; mi < 2; ++mi)
      #pragma unroll
      for (int ni = 0; ni < 4; ++ni)
        acc[mi][ni] = __builtin_amdgcn_mfma_f32_16x16x32_bf16(af[mi], bfr[ni], acc[mi][ni], 0, 0, 0);
    DRAIN_LGKM();
    __syncthreads();
  }

  #pragma unroll
  for (int mi = 0; mi < 2; ++mi)
    #pragma unroll
    for (int ni = 0; ni < 4; ++ni) {
      const int col = n0 + ni * 16 + lr;
      const float bv = bias[col];
      #pragma unroll
      for (int r = 0; r < 4; ++r) {
        const int row = m0 + wv * 32 + mi * 16 + lg * 4 + r;
        Cout[(size_t)row * DMODEL + col] = acc[mi][ni][r] + bv;
      }
    }
}

// ---------------- flash attention (causal): balanced barrier-free waves ----------------
// Q,K: [B,H,S,DK]  V: [B,H,DK,S]  O: [B,S,D] bf16
// Each WAVE owns the 16-row chunk pair (p, 127-p): exactly 33 KV tiles
// (floor(p/4)+floor((127-p)/4) == 31 for all p). 4 independent waves packed
// per 256-thr block (no barriers, no shared state): 512 blocks = 2 blocks/CU
// = 8 waves/CU, all resident, uniform finish. XCD-pinned (bid&7 = XCD, 4 bh
// per XCD -> K/V L2-resident, proven FETCH 16MB). Per tile, V[t] and K[t+1]
// loads issue BEFORE QK^T/softmax so L2 latency hides under VALU work; K[t]
// is always already in registers (2-deep static-indexed prefetch, rule #20).
__device__ __forceinline__ void attn_tile(
    int t, int nt, int QR, int lr, int lg,
    const __bf16* __restrict__ Kb, const __bf16* __restrict__ Vb,
    const float* __restrict__ pm, char* pldsw,
    const bf16x8& qf0, const bf16x8& qf1,
    bf16x8 (&kc)[4][2], bf16x8 (&kn)[4][2],
    float& mrow, float& lrw, f32x4 (&oacc)[4],
    float SCL, float L2E) {
  const int tn = (t + 1 < nt) ? (t + 1) : t;   // clamped prefetch
  // ---- V loads for tile t (needed ~600cyc later at PV) ----
  bf16x8 vf[4][2];
  #pragma unroll
  for (int og = 0; og < 4; ++og) {
    const __bf16* vrow = &Vb[(size_t)(og * 16 + lr) * SEQ + t * 64 + lg * 8];
    vf[og][0] = *(const bf16x8*)vrow;
    vf[og][1] = *(const bf16x8*)(vrow + 32);
  }
  // ---- K prefetch for tile t+1 (needed next iteration) ----
  #pragma unroll
  for (int g = 0; g < 4; ++g) {
    const __bf16* krow = &Kb[(size_t)(tn * 64 + g * 16 + lr) * DK + lg * 8];
    kn[g][0] = *(const bf16x8*)krow;
    kn[g][1] = *(const bf16x8*)(krow + 32);
  }
  // ---- S^T = K Q^T from current K registers ----
  f32x4 sc[4];
  #pragma unroll
  for (int g = 0; g < 4; ++g) {
    f32x4 a = {};
    a = __builtin_amdgcn_mfma_f32_16x16x32_bf16(kc[g][0], qf0, a, 0, 0, 0);
    a = __builtin_amdgcn_mfma_f32_16x16x32_bf16(kc[g][1], qf1, a, 0, 0, 0);
    sc[g] = a;   // sc[g][r] = S[q=QR+lr][kv=t*64+g*16+lg*4+r]
  }
  // ---- scale + padding + causal masks (log2 domain) ----
  const bool edge = (t == nt - 1);
  #pragma unroll
  for (int g = 0; g < 4; ++g) {
    const float4 pmv = *(const float4*)&pm[t * 64 + g * 16 + lg * 4];
    const float pmf[4] = {pmv.x, pmv.y, pmv.z, pmv.w};
    #pragma unroll
    for (int r = 0; r < 4; ++r) {
      float s = sc[g][r] * SCL + pmf[r] * L2E;
      if (edge && (t * 64 + g * 16 + lg * 4 + r > QR + lr)) s = -1e30f;
      sc[g][r] = s;
    }
  }
  // ---- online softmax: lane owns full q-row lr ----
  float pmax = sc[0][0];
  #pragma unroll
  for (int g = 0; g < 4; ++g)
    #pragma unroll
    for (int r = 0; r < 4; ++r) pmax = fmaxf(pmax, sc[g][r]);
  pmax = fmaxf(pmax, __shfl_xor(pmax, 16, 64));
  pmax = fmaxf(pmax, __shfl_xor(pmax, 32, 64));
  const float mnew = fmaxf(mrow, pmax);
  const float alpha = exp2f(mrow - mnew);
  mrow = mnew;
  float psum = 0.f;
  #pragma unroll
  for (int g = 0; g < 4; ++g)
    #pragma unroll
    for (int r = 0; r < 4; ++r) {
      float p = exp2f(sc[g][r] - mnew);
      sc[g][r] = p;
      psum += p;
    }
  psum += __shfl_xor(psum, 16, 64);
  psum += __shfl_xor(psum, 32, 64);
  lrw = lrw * alpha + psum;
  // ---- rescale O rows (q = lg*4+r) ----
  #pragma unroll
  for (int r = 0; r < 4; ++r) {
    const float av = __shfl(alpha, lg * 4 + r, 64);
    #pragma unroll
    for (int og = 0; og < 4; ++og) oacc[og][r] *= av;
  }
  // ---- P -> wave-private LDS (bf16, XOR swizzle (row&7)<<4) ----
  #pragma unroll
  for (int g = 0; g < 4; ++g) {
    bf16x4 pk = { (__bf16)sc[g][0], (__bf16)sc[g][1], (__bf16)sc[g][2], (__bf16)sc[g][3] };
    const int byteoff = lr * 128 + ((g * 32 + lg * 8) ^ ((lr & 7) << 4));
    *(bf16x4*)(pldsw + byteoff) = pk;
  }
  // ---- PV: O += P V ----
  #pragma unroll
  for (int kk = 0; kk < 2; ++kk) {
    const int pboff = lr * 128 + ((kk * 64 + lg * 16) ^ ((lr & 7) << 4));
    const bf16x8 pa = *(const bf16x8*)(pldsw + pboff);
    #pragma unroll
    for (int og = 0; og < 4; ++og)
      oacc[og] = __builtin_amdgcn_mfma_f32_16x16x32_bf16(pa, vf[og][kk], oacc[og], 0, 0, 0);
  }
}

__global__ __launch_bounds__(256, 2) void k_attn(const __bf16* __restrict__ Q,
                                                 const __bf16* __restrict__ Kt,
                                                 const __bf16* __restrict__ Vt,
                                                 const float* __restrict__ pmask,
                                                 __bf16* __restrict__ O) {
  __shared__ __align__(16) __bf16 plds[4][16 * 64];  // 4 x 2KB wave-private
  const int lane = threadIdx.x & 63, wv = threadIdx.x >> 6;
  const int lr = lane & 15, lg = lane >> 4;
  char* pldsw = (char*)plds[wv];

  const int bid = blockIdx.x;
  const int xcd = bid & 7;
  const int rdec = bid >> 3;      // 0..63
  const int slot = rdec >> 4;     // 0..3
  const int pb = rdec & 15;       // 0..15
  const int bh = slot * 8 + xcd;
  const int b = bh >> 4, h = bh & 15;
  const int p = pb * 4 + wv;      // this wave's pair index, 0..63

  const __bf16* Qb = Q + (size_t)bh * SEQ * DK;
  const __bf16* Kb = Kt + (size_t)bh * SEQ * DK;
  const __bf16* Vb = Vt + (size_t)bh * DK * SEQ;
  const float* pm = pmask + (size_t)b * SEQ;
  const float SCL = 0.125f * 1.44269504f;   // 1/sqrt(dk) * log2(e)
  const float L2E = 1.44269504f;

  #pragma unroll
  for (int half = 0; half < 2; ++half) {
    const int c = half ? (127 - p) : p;   // 16-row chunk index
    const int QR = c * 16;
    const int nt = (c >> 2) + 1;

    const bf16x8 qf0 = *(const bf16x8*)&Qb[(size_t)(QR + lr) * DK + lg * 8];
    const bf16x8 qf1 = *(const bf16x8*)&Qb[(size_t)(QR + lr) * DK + 32 + lg * 8];

    float mrow = -1e30f, lrw = 0.f;
    f32x4 oacc[4] = {};

    // preload K tile 0 into set A
    bf16x8 kA[4][2], kB[4][2];
    #pragma unroll
    for (int g = 0; g < 4; ++g) {
      const __bf16* krow = &Kb[(size_t)(g * 16 + lr) * DK + lg * 8];
      kA[g][0] = *(const bf16x8*)krow;
      kA[g][1] = *(const bf16x8*)(krow + 32);
    }

    int t = 0;
    while (true) {   // 2-deep static-indexed prefetch ping-pong (rule #20)
      attn_tile(t, nt, QR, lr, lg, Kb, Vb, pm, pldsw, qf0, qf1,
                kA, kB, mrow, lrw, oacc, SCL, L2E);
      if (++t >= nt) break;
      attn_tile(t, nt, QR, lr, lg, Kb, Vb, pm, pldsw, qf0, qf1,
                kB, kA, mrow, lrw, oacc, SCL, L2E);
      if (++t >= nt) break;
    }

    // ---- epilogue: normalize, write O [B,S,H*DK] ----
    #pragma unroll
    for (int r = 0; r < 4; ++r) {
      const float lsh = __shfl(lrw, lg * 4 + r, 64);
      const float inv = 1.f / lsh;
      const int row = QR + lg * 4 + r;
      #pragma unroll
      for (int og = 0; og < 4; ++og)
        O[((size_t)b * SEQ + row) * DMODEL + h * DK + og * 16 + lr] = (__bf16)(oacc[og][r] * inv);
    }
  }
}

extern "C" void kernel_launch(void* const* d_in, const int* in_sizes, int n_in,
                              void* d_out, int out_size, void* d_ws, size_t ws_size,
                              hipStream_t stream) {
  (void)in_sizes; (void)n_in; (void)out_size; (void)ws_size;
  const float* query = (const float*)d_in[0];
  const float* key   = (const float*)d_in[1];
  const float* value = (const float*)d_in[2];
  const float* pmask = (const float*)d_in[3];
  const float* w_q = (const float*)d_in[5];
  const float* w_k = (const float*)d_in[6];
  const float* w_v = (const float*)d_in[7];
  const float* w_o = (const float*)d_in[8];
  const float* b_q = (const float*)d_in[9];
  const float* b_k = (const float*)d_in[10];
  const float* b_v = (const float*)d_in[11];
  const float* b_o = (const float*)d_in[12];

  __bf16* ws = (__bf16*)d_ws;
  const size_t WSZ = (size_t)DMODEL * DMODEL;  // 1M elems
  const size_t XSZ = (size_t)MTOT * DMODEL;    // 4M elems
  __bf16* WTq = ws;
  __bf16* WTk = WTq + WSZ;
  __bf16* WTv = WTk + WSZ;
  __bf16* WTo = WTv + WSZ;
  __bf16* Xq  = WTo + WSZ;
  __bf16* Xk  = Xq + XSZ;
  __bf16* Xv  = Xk + XSZ;
  __bf16* Qh  = Xv + XSZ;
  __bf16* Kh  = Qh + XSZ;
  __bf16* Vh  = Kh + XSZ;
  __bf16* Oh  = Xq;  // alias: Xq dead after q projection

  dim3 blk(256);
  k_cvt3<<<dim3(4096, 3), blk, 0, stream>>>(query, key, value, Xq, Xk, Xv, (int)(XSZ / 4));
  k_transpose4<<<dim3(32, 32, 4), blk, 0, stream>>>(w_q, w_k, w_v, w_o, WTq, WTk, WTv, WTo);

  k_gemm_qkv<<<dim3(16, 32, 3), blk, 0, stream>>>(Xq, Xk, Xv, WTq, WTk, WTv,
                                                  b_q, b_k, b_v, Qh, Kh, Vh);

  k_attn<<<dim3(512), blk, 0, stream>>>(Qh, Kh, Vh, pmask, Oh);

  k_gemm_out<<<dim3(16, 32), blk, 0, stream>>>(Oh, WTo, b_o, (float*)d_out);
}

// Round 8
// 145.446 us; speedup vs baseline: 1.6210x; 1.6210x over previous
//
#include <hip/hip_runtime.h>
#include <hip/hip_bf16.h>
#include <stdint.h>

typedef __bf16 bf16x8 __attribute__((ext_vector_type(8)));
typedef __bf16 bf16x4 __attribute__((ext_vector_type(4)));
typedef float f32x4 __attribute__((ext_vector_type(4)));

#define DMODEL 1024
#define SEQ    2048
#define NHEAD  16
#define DK     64
#define MTOT   4096
#define KDIM   1024

// Explicit ISA-level drain before barriers that close a staging protocol
// (round-4 post-timing divergence fix; measured free).
#define DRAIN_VM_LGKM() asm volatile("s_waitcnt vmcnt(0) lgkmcnt(0)" ::: "memory")
#define DRAIN_LGKM()    asm volatile("s_waitcnt lgkmcnt(0)" ::: "memory")

__device__ __forceinline__ void gl2lds16(const void* g, void* l) {
  __builtin_amdgcn_global_load_lds((__attribute__((address_space(1))) void*)(g),
                                   (__attribute__((address_space(3))) void*)(l),
                                   16, 0, 0);
}

// ---------------- prep: f32 -> bf16 convert, q/k/v batched ----------------
__global__ __launch_bounds__(256) void k_cvt3(const float* __restrict__ q,
                                              const float* __restrict__ k,
                                              const float* __restrict__ v,
                                              __bf16* __restrict__ oq,
                                              __bf16* __restrict__ ok,
                                              __bf16* __restrict__ ov,
                                              int n4) {
  const int which = blockIdx.y;
  const float* in = which == 0 ? q : (which == 1 ? k : v);
  __bf16* out = which == 0 ? oq : (which == 1 ? ok : ov);
  const int i = blockIdx.x * 256 + threadIdx.x;
  if (i >= n4) return;
  const float4 f = ((const float4*)in)[i];
  bf16x4 o = { (__bf16)f.x, (__bf16)f.y, (__bf16)f.z, (__bf16)f.w };
  ((bf16x4*)out)[i] = o;
}

// ---------------- prep: W [K][N] f32 -> WT [N][K] bf16, 4 weights batched ----------------
__global__ __launch_bounds__(256) void k_transpose4(const float* __restrict__ w0,
                                                    const float* __restrict__ w1,
                                                    const float* __restrict__ w2,
                                                    const float* __restrict__ w3,
                                                    __bf16* __restrict__ t0,
                                                    __bf16* __restrict__ t1,
                                                    __bf16* __restrict__ t2,
                                                    __bf16* __restrict__ t3) {
  const int z = blockIdx.z;
  const float* W = z == 0 ? w0 : (z == 1 ? w1 : (z == 2 ? w2 : w3));
  __bf16* WT = z == 0 ? t0 : (z == 1 ? t1 : (z == 2 ? t2 : t3));
  __shared__ float tile[32][33];
  int n0 = blockIdx.x * 32, k0 = blockIdx.y * 32;
  int tx = threadIdx.x & 31, ty = threadIdx.x >> 5;
  #pragma unroll
  for (int i = ty; i < 32; i += 8)
    tile[i][tx] = W[(size_t)(k0 + i) * DMODEL + n0 + tx];
  __syncthreads();
  #pragma unroll
  for (int i = ty; i < 32; i += 8)
    WT[(size_t)(n0 + i) * DMODEL + k0 + tx] = (__bf16)tile[tx][i];
}

// ---------------- batched projection GEMM: z in {q,k,v}, 128x128 (round-5 proven) ----------------
__global__ __launch_bounds__(256) void k_gemm_qkv(
    const __bf16* __restrict__ A0, const __bf16* __restrict__ A1, const __bf16* __restrict__ A2,
    const __bf16* __restrict__ W0, const __bf16* __restrict__ W1, const __bf16* __restrict__ W2,
    const float* __restrict__ bi0, const float* __restrict__ bi1, const float* __restrict__ bi2,
    __bf16* __restrict__ C0, __bf16* __restrict__ C1, __bf16* __restrict__ C2) {
  const int z = blockIdx.z;
  const __bf16* A  = z == 0 ? A0 : (z == 1 ? A1 : A2);
  const __bf16* BT = z == 0 ? W0 : (z == 1 ? W1 : W2);
  const float* bias = z == 0 ? bi0 : (z == 1 ? bi1 : bi2);
  __bf16* Cout = z == 0 ? C0 : (z == 1 ? C1 : C2);

  __shared__ __align__(16) __bf16 As[128 * 32];
  __shared__ __align__(16) __bf16 Bs[128 * 32];
  const int tid = threadIdx.x;
  const int lane = tid & 63;
  const int wv = tid >> 6;
  const int wm = wv >> 1, wn = wv & 1;
  const int m0 = blockIdx.y * 128, n0 = blockIdx.x * 128;
  const int lr = lane & 15, lg = lane >> 4;

  f32x4 acc[4][4] = {};

  for (int k0 = 0; k0 < KDIM; k0 += 32) {
    #pragma unroll
    for (int i = 0; i < 2; ++i) {
      int c = tid + i * 256;
      int row = c >> 2, seg = c & 3;
      gl2lds16(A + (size_t)(m0 + row) * KDIM + k0 + seg * 8, (char*)As + c * 16);
      gl2lds16(BT + (size_t)(n0 + row) * KDIM + k0 + seg * 8, (char*)Bs + c * 16);
    }
    DRAIN_VM_LGKM();
    __syncthreads();
    bf16x8 af[4], bfr[4];
    #pragma unroll
    for (int mi = 0; mi < 4; ++mi)
      af[mi] = *(const bf16x8*)&As[(wm * 64 + mi * 16 + lr) * 32 + lg * 8];
    #pragma unroll
    for (int ni = 0; ni < 4; ++ni)
      bfr[ni] = *(const bf16x8*)&Bs[(wn * 64 + ni * 16 + lr) * 32 + lg * 8];
    #pragma unroll
    for (int mi = 0; mi < 4; ++mi)
      #pragma unroll
      for (int ni = 0; ni < 4; ++ni)
        acc[mi][ni] = __builtin_amdgcn_mfma_f32_16x16x32_bf16(af[mi], bfr[ni], acc[mi][ni], 0, 0, 0);
    DRAIN_LGKM();
    __syncthreads();
  }

  #pragma unroll
  for (int mi = 0; mi < 4; ++mi)
    #pragma unroll
    for (int ni = 0; ni < 4; ++ni) {
      const int col = n0 + wn * 64 + ni * 16 + lr;
      const float bv = bias[col];
      #pragma unroll
      for (int r = 0; r < 4; ++r) {
        const int row = m0 + wm * 64 + mi * 16 + lg * 4 + r;
        float v = acc[mi][ni][r] + bv;
        const int b = row >> 11, s = row & (SEQ - 1);
        const int h = col >> 6, dd = col & (DK - 1);
        if (z == 2)
          Cout[((size_t)(b * NHEAD + h) * DK + dd) * SEQ + s] = (__bf16)v;
        else
          Cout[((size_t)(b * NHEAD + h) * SEQ + s) * DK + dd] = (__bf16)v;
      }
    }
}

// ---------------- final GEMM: f32 out + bias, 128x128 (round-5 proven) ----------------
__global__ __launch_bounds__(256) void k_gemm_out(const __bf16* __restrict__ A,
                                                  const __bf16* __restrict__ BT,
                                                  const float* __restrict__ bias,
                                                  float* __restrict__ Cout) {
  __shared__ __align__(16) __bf16 As[128 * 32];
  __shared__ __align__(16) __bf16 Bs[128 * 32];
  const int tid = threadIdx.x;
  const int lane = tid & 63;
  const int wv = tid >> 6;
  const int wm = wv >> 1, wn = wv & 1;
  const int m0 = blockIdx.y * 128, n0 = blockIdx.x * 128;
  const int lr = lane & 15, lg = lane >> 4;

  f32x4 acc[4][4] = {};

  for (int k0 = 0; k0 < KDIM; k0 += 32) {
    #pragma unroll
    for (int i = 0; i < 2; ++i) {
      int c = tid + i * 256;
      int row = c >> 2, seg = c & 3;
      gl2lds16(A + (size_t)(m0 + row) * KDIM + k0 + seg * 8, (char*)As + c * 16);
      gl2lds16(BT + (size_t)(n0 + row) * KDIM + k0 + seg * 8, (char*)Bs + c * 16);
    }
    DRAIN_VM_LGKM();
    __syncthreads();
    bf16x8 af[4], bfr[4];
    #pragma unroll
    for (int mi = 0; mi < 4; ++mi)
      af[mi] = *(const bf16x8*)&As[(wm * 64 + mi * 16 + lr) * 32 + lg * 8];
    #pragma unroll
    for (int ni = 0; ni < 4; ++ni)
      bfr[ni] = *(const bf16x8*)&Bs[(wn * 64 + ni * 16 + lr) * 32 + lg * 8];
    #pragma unroll
    for (int mi = 0; mi < 4; ++mi)
      #pragma unroll
      for (int ni = 0; ni < 4; ++ni)
        acc[mi][ni] = __builtin_amdgcn_mfma_f32_16x16x32_bf16(af[mi], bfr[ni], acc[mi][ni], 0, 0, 0);
    DRAIN_LGKM();
    __syncthreads();
  }

  #pragma unroll
  for (int mi = 0; mi < 4; ++mi)
    #pragma unroll
    for (int ni = 0; ni < 4; ++ni) {
      const int col = n0 + wn * 64 + ni * 16 + lr;
      const float bv = bias[col];
      #pragma unroll
      for (int r = 0; r < 4; ++r) {
        const int row = m0 + wm * 64 + mi * 16 + lg * 4 + r;
        Cout[(size_t)row * DMODEL + col] = acc[mi][ni][r] + bv;
      }
    }
}

// ---------------- flash attention (causal), KVBLK=128, 4-wave blocks ----------------
// Round-3 proven skeleton (best measured: 84us) with KVBLK 64->128:
// barrier rounds per block 33->17, per-tile softmax fixed costs amortized
// over 2x KV. Block = 4 waves, owns 64-row chunk pair (qb, 31-qb): exactly
// 17 128-wide KV tiles. LDS 80KB -> 2 blocks/CU (= grid cap 512/256, nothing
// lost). XCD-pinned (bid&7): K/V L2-resident (proven FETCH 12MB). T13
// defer-max: skip O-rescale when __all(pmax <= m+8) (log2 domain, P<=256 safe).
__global__ __launch_bounds__(256, 2) void k_attn(const __bf16* __restrict__ Q,
                                                 const __bf16* __restrict__ Kt,
                                                 const __bf16* __restrict__ Vt,
                                                 const float* __restrict__ pmask,
                                                 __bf16* __restrict__ O) {
  __shared__ __align__(16) __bf16 Ks[2][128 * 64];   // 2 x 16KB (128 kv-rows x 64 dk)
  __shared__ __align__(16) __bf16 Vs[2][64 * 128];   // 2 x 16KB (64 dk-rows x 128 kv)
  __shared__ __align__(16) __bf16 plds[4][16 * 128]; // 4 x 4KB wave-private P

  const int tid = threadIdx.x;
  const int lane = tid & 63, wv = tid >> 6;
  const int lr = lane & 15, lg = lane >> 4;

  // bid = xcd + 8*(slot*16 + pair): all 16 pair-blocks of bh=slot*8+xcd on one XCD
  const int bid = blockIdx.x;
  const int xcd = bid & 7;
  const int rdec = bid >> 3;
  const int slot = rdec >> 4;   // 0..3
  const int pair = rdec & 15;   // 0..15
  const int bh = slot * 8 + xcd;
  const int b = bh >> 4, h = bh & 15;

  const __bf16* Qb = Q + (size_t)bh * SEQ * DK;
  const __bf16* Kb = Kt + (size_t)bh * SEQ * DK;
  const __bf16* Vb = Vt + (size_t)bh * DK * SEQ;
  const float* pm = pmask + (size_t)b * SEQ;
  const float SCL = 0.125f * 1.44269504f;   // 1/sqrt(dk) * log2(e)
  const float L2E = 1.44269504f;

  // stage 128-wide K/V tile t into buffer buf: linear LDS dest,
  // inverse-swizzled source (x ^= (row&7)<<4), 8 gl2lds per thread
  auto stage = [&](int buf, int t) {
    #pragma unroll
    for (int i = 0; i < 4; ++i) {
      const int c = tid + i * 256;              // 1024 x 16B chunks (K)
      const int row = c >> 3;                   // 0..127
      const int sx = ((c & 7) * 16) ^ ((row & 7) << 4);
      gl2lds16((const char*)Kb + (size_t)(t * 128 + row) * 128 + sx,
               (char*)&Ks[buf][0] + c * 16);
    }
    #pragma unroll
    for (int i = 0; i < 4; ++i) {
      const int c = tid + i * 256;              // 1024 x 16B chunks (V)
      const int row = c >> 4;                   // 0..63
      const int sx = ((c & 15) * 16) ^ ((row & 7) << 4);
      gl2lds16((const char*)Vb + (size_t)row * (SEQ * 2) + (size_t)t * 256 + sx,
               (char*)&Vs[buf][0] + c * 16);
    }
  };

  for (int half = 0; half < 2; ++half) {
    const int qb = half ? (31 - pair) : pair;   // 64-row Q chunk index
    const int nt = (qb + 2) >> 1;               // causal 128-wide KV tiles
    const int QR = qb * 64 + wv * 16;           // this wave's first Q row

    const bf16x8 qf0 = *(const bf16x8*)&Qb[(size_t)(QR + lr) * DK + lg * 8];
    const bf16x8 qf1 = *(const bf16x8*)&Qb[(size_t)(QR + lr) * DK + 32 + lg * 8];

    float mrow = -1e30f, lrw = 0.f;    // q-row = lr (log2 domain)
    f32x4 oacc[4] = {};                // [og]: row q=lg*4+r, col d=og*16+lr

    stage(0, 0);
    DRAIN_VM_LGKM();
    __syncthreads();
    int cur = 0;
    for (int t = 0; t < nt; ++t) {
      if (t + 1 < nt) stage(cur ^ 1, t + 1);
      // ---- S^T = K Q^T (8 groups of 16 kv) ----
      f32x4 sc[8];
      #pragma unroll
      for (int g = 0; g < 8; ++g) {
        const int krow = g * 16 + lr;
        const int ksw = (lr & 7) << 4;
        bf16x8 kf0 = *(const bf16x8*)((const char*)&Ks[cur][0] + krow * 128 + ((lg * 16) ^ ksw));
        bf16x8 kf1 = *(const bf16x8*)((const char*)&Ks[cur][0] + krow * 128 + ((64 + lg * 16) ^ ksw));
        f32x4 a = {};
        a = __builtin_amdgcn_mfma_f32_16x16x32_bf16(kf0, qf0, a, 0, 0, 0);
        a = __builtin_amdgcn_mfma_f32_16x16x32_bf16(kf1, qf1, a, 0, 0, 0);
        sc[g] = a;   // sc[g][r] = S[q=QR+lr][kv=t*128+g*16+lg*4+r]
      }
      // ---- scale + padding + causal masks (log2 domain) ----
      const bool edge = (t == nt - 1);
      #pragma unroll
      for (int g = 0; g < 8; ++g) {
        const float4 pmv = *(const float4*)&pm[t * 128 + g * 16 + lg * 4];
        const float pmf[4] = {pmv.x, pmv.y, pmv.z, pmv.w};
        #pragma unroll
        for (int r = 0; r < 4; ++r) {
          float s = sc[g][r] * SCL + pmf[r] * L2E;
          if (edge && (t * 128 + g * 16 + lg * 4 + r > QR + lr)) s = -1e30f;
          sc[g][r] = s;
        }
      }
      // ---- online softmax, defer-max (T13) ----
      float pmax = sc[0][0];
      #pragma unroll
      for (int g = 0; g < 8; ++g)
        #pragma unroll
        for (int r = 0; r < 4; ++r) pmax = fmaxf(pmax, sc[g][r]);
      pmax = fmaxf(pmax, __shfl_xor(pmax, 16, 64));
      pmax = fmaxf(pmax, __shfl_xor(pmax, 32, 64));
      if (!__all(pmax <= mrow + 8.f)) {
        const float mnew = fmaxf(mrow, pmax);
        const float alpha = exp2f(mrow - mnew);
        mrow = mnew;
        lrw *= alpha;
        #pragma unroll
        for (int r = 0; r < 4; ++r) {
          const float av = __shfl(alpha, lg * 4 + r, 64);
          #pragma unroll
          for (int og = 0; og < 4; ++og) oacc[og][r] *= av;
        }
      }
      float psum = 0.f;
      #pragma unroll
      for (int g = 0; g < 8; ++g)
        #pragma unroll
        for (int r = 0; r < 4; ++r) {
          float p = exp2f(sc[g][r] - mrow);
          sc[g][r] = p;
          psum += p;
        }
      psum += __shfl_xor(psum, 16, 64);
      psum += __shfl_xor(psum, 32, 64);
      lrw += psum;
      // ---- P -> wave-private LDS (bf16, XOR swizzle (row&7)<<4) ----
      #pragma unroll
      for (int g = 0; g < 8; ++g) {
        bf16x4 pk = { (__bf16)sc[g][0], (__bf16)sc[g][1], (__bf16)sc[g][2], (__bf16)sc[g][3] };
        const int byteoff = lr * 256 + ((g * 32 + lg * 8) ^ ((lr & 7) << 4));
        *(bf16x4*)((char*)plds[wv] + byteoff) = pk;
      }
      // ---- PV: O += P V (4 k-slices of 32 kv) ----
      #pragma unroll
      for (int kk = 0; kk < 4; ++kk) {
        const int pboff = lr * 256 + ((kk * 64 + lg * 16) ^ ((lr & 7) << 4));
        const bf16x8 pa = *(const bf16x8*)((char*)plds[wv] + pboff);
        #pragma unroll
        for (int og = 0; og < 4; ++og) {
          const int vrow = og * 16 + lr;
          const bf16x8 vf = *(const bf16x8*)((const char*)&Vs[cur][0] + vrow * 256 + ((kk * 64 + lg * 16) ^ ((lr & 7) << 4)));
          oacc[og] = __builtin_amdgcn_mfma_f32_16x16x32_bf16(pa, vf, oacc[og], 0, 0, 0);
        }
      }
      DRAIN_VM_LGKM();   // my stage loads landed (RAW for t+1) + ds ops done (WAR)
      __syncthreads();
      cur ^= 1;
    }

    // ---- epilogue: normalize, write O [B,S,H*DK] ----
    #pragma unroll
    for (int r = 0; r < 4; ++r) {
      const float lsh = __shfl(lrw, lg * 4 + r, 64);
      const float inv = 1.f / lsh;
      const int row = QR + lg * 4 + r;
      #pragma unroll
      for (int og = 0; og < 4; ++og)
        O[((size_t)b * SEQ + row) * DMODEL + h * DK + og * 16 + lr] = (__bf16)(oacc[og][r] * inv);
    }
  }
}

extern "C" void kernel_launch(void* const* d_in, const int* in_sizes, int n_in,
                              void* d_out, int out_size, void* d_ws, size_t ws_size,
                              hipStream_t stream) {
  (void)in_sizes; (void)n_in; (void)out_size; (void)ws_size;
  const float* query = (const float*)d_in[0];
  const float* key   = (const float*)d_in[1];
  const float* value = (const float*)d_in[2];
  const float* pmask = (const float*)d_in[3];
  const float* w_q = (const float*)d_in[5];
  const float* w_k = (const float*)d_in[6];
  const float* w_v = (const float*)d_in[7];
  const float* w_o = (const float*)d_in[8];
  const float* b_q = (const float*)d_in[9];
  const float* b_k = (const float*)d_in[10];
  const float* b_v = (const float*)d_in[11];
  const float* b_o = (const float*)d_in[12];

  __bf16* ws = (__bf16*)d_ws;
  const size_t WSZ = (size_t)DMODEL * DMODEL;  // 1M elems
  const size_t XSZ = (size_t)MTOT * DMODEL;    // 4M elems
  __bf16* WTq = ws;
  __bf16* WTk = WTq + WSZ;
  __bf16* WTv = WTk + WSZ;
  __bf16* WTo = WTv + WSZ;
  __bf16* Xq  = WTo + WSZ;
  __bf16* Xk  = Xq + XSZ;
  __bf16* Xv  = Xk + XSZ;
  __bf16* Qh  = Xv + XSZ;
  __bf16* Kh  = Qh + XSZ;
  __bf16* Vh  = Kh + XSZ;
  __bf16* Oh  = Xq;  // alias: Xq dead after q projection

  dim3 blk(256);
  k_cvt3<<<dim3(4096, 3), blk, 0, stream>>>(query, key, value, Xq, Xk, Xv, (int)(XSZ / 4));
  k_transpose4<<<dim3(32, 32, 4), blk, 0, stream>>>(w_q, w_k, w_v, w_o, WTq, WTk, WTv, WTo);

  k_gemm_qkv<<<dim3(8, 32, 3), blk, 0, stream>>>(Xq, Xk, Xv, WTq, WTk, WTv,
                                                 b_q, b_k, b_v, Qh, Kh, Vh);

  k_attn<<<dim3(512), blk, 0, stream>>>(Qh, Kh, Vh, pmask, Oh);

  k_gemm_out<<<dim3(8, 32), blk, 0, stream>>>(Oh, WTo, b_o, (float*)d_out);
}